// Round 2
// baseline (328.084 us; speedup 1.0000x reference)
//
#include <hip/hip_runtime.h>
#include <hip/hip_bf16.h>
#include <math.h>

typedef __attribute__((ext_vector_type(8))) short  short8;
typedef __attribute__((ext_vector_type(4))) float  f32x4;
typedef __attribute__((ext_vector_type(4))) unsigned short u16x4;
typedef __attribute__((ext_vector_type(8))) unsigned short u16x8;

#define BATCH 16384
#define NF    64
#define BAGL  10
#define ED    16
#define DW    1024   // F*E

static __device__ __forceinline__ unsigned short f2bf(float f) {
    unsigned int u = __builtin_bit_cast(unsigned int, f);
    unsigned int r = (u + 0x7fffu + ((u >> 16) & 1u)) >> 16;
    return (unsigned short)r;
}
static __device__ __forceinline__ float bf2f(unsigned short h) {
    unsigned int u = ((unsigned int)h) << 16;
    return __builtin_bit_cast(float, u);
}

// ---------------- 1. embedding gather + bag-sum, write bf16 x [B,1024] -----
// 4 threads per bag, 16B per thread per row. All 10 gathers issued before any
// accumulation so each wave keeps 10 loads in flight (MLP fix: was 24 VGPRs /
// ~2 outstanding -> latency-bound at 3.5 TB/s).
__global__ __launch_bounds__(256) void pool_kernel(const int* __restrict__ idx,
                                                   const float* __restrict__ emb,
                                                   unsigned short* __restrict__ xb) {
    const int gid = blockIdx.x * 256 + threadIdx.x;   // B*F*4 threads
    const int bag = gid >> 2;                         // b*F + f
    const int q   = gid & 3;                          // which float4 of E=16
    const int* ip = idx + (long long)bag * BAGL;

    int v[BAGL];
#pragma unroll
    for (int l = 0; l < BAGL; ++l) v[l] = ip[l];

    f32x4 e[BAGL];
#pragma unroll
    for (int l = 0; l < BAGL; ++l)
        e[l] = *(const f32x4*)(emb + (((long long)v[l]) << 4) + (q << 2));

    // pairwise tree sum (short dependency chain)
    f32x4 s01 = e[0] + e[1], s23 = e[2] + e[3], s45 = e[4] + e[5],
          s67 = e[6] + e[7], s89 = e[8] + e[9];
    f32x4 t0 = s01 + s23, t1 = s45 + s67;
    f32x4 acc = (t0 + t1) + s89;

    u16x4 o;
#pragma unroll
    for (int j = 0; j < 4; ++j) o[j] = f2bf(acc[j]);
    *(u16x4*)(xb + (((long long)bag) << 4) + (q << 2)) = o;
}

// ---------------- 2. per-column sum / sumsq over batch ---------------------
__global__ __launch_bounds__(256) void stats_kernel(const unsigned short* __restrict__ xb,
                                                    float* __restrict__ ssum,
                                                    float* __restrict__ ssq) {
    const int t = threadIdx.x;                 // cols 4t..4t+3
    const long long r0 = (long long)blockIdx.x * 128;
    float s[4] = {0, 0, 0, 0}, q[4] = {0, 0, 0, 0};
    for (int r = 0; r < 128; ++r) {
        const u16x4 v = *(const u16x4*)(xb + (r0 + r) * DW + t * 4);
#pragma unroll
        for (int j = 0; j < 4; ++j) { float f = bf2f(v[j]); s[j] += f; q[j] += f * f; }
    }
#pragma unroll
    for (int j = 0; j < 4; ++j) {
        atomicAdd(&ssum[t * 4 + j], s[j]);
        atomicAdd(&ssq [t * 4 + j], q[j]);
    }
}

__global__ void finalize_stats(const float* __restrict__ ssum, const float* __restrict__ ssq,
                               float* __restrict__ mean, float* __restrict__ rsig) {
    const int c = blockIdx.x * 256 + threadIdx.x;    // 1024 total
    const float m = ssum[c] * (1.0f / (float)BATCH);
    const float v = ssq[c] * (1.0f / (float)BATCH) - m * m;
    mean[c] = m;
    rsig[c] = rsqrtf(v + 1e-5f);
}

// ---------------- 3. normalize x in place ----------------------------------
__global__ __launch_bounds__(256) void normalize_kernel(unsigned short* __restrict__ xb,
                                                        const float* __restrict__ mean,
                                                        const float* __restrict__ rsig) {
    const long long gid = (long long)blockIdx.x * 256 + threadIdx.x;
    const long long off = gid * 8;
    const int c0 = (int)(off & (DW - 1));
    u16x8 v = *(u16x8*)(xb + off);
#pragma unroll
    for (int j = 0; j < 8; ++j) {
        float f = (bf2f(v[j]) - mean[c0 + j]) * rsig[c0 + j];
        v[j] = f2bf(f);
    }
    *(u16x8*)(xb + off) = v;
}

// ---------------- 4. W [R,C] f32 -> Wt [C,R] bf16 ---------------------------
__global__ __launch_bounds__(256) void transpose_f32_bf16(const float* __restrict__ src,
                                                          unsigned short* __restrict__ dst,
                                                          int R, int C) {
    __shared__ float tile[32][33];
    const int tx = threadIdx.x & 31, ty = threadIdx.x >> 5;
    const int bx = blockIdx.x, by = blockIdx.y;
#pragma unroll
    for (int i = 0; i < 4; ++i) {
        const int r = by * 32 + ty + i * 8, c = bx * 32 + tx;
        tile[ty + i * 8][tx] = src[(long long)r * C + c];
    }
    __syncthreads();
#pragma unroll
    for (int i = 0; i < 4; ++i) {
        const int oc = bx * 32 + ty + i * 8;     // column index -> row of dst
        dst[(long long)oc * R + by * 32 + tx] = f2bf(tile[tx][ty + i * 8]);
    }
}

// ---------------- 5. bf16 MFMA GEMM: C = act(A @ Bt^T + bias) --------------
// A [M,K] bf16 row-major, Bt [N,K] bf16 row-major, C [M,N] bf16, 128x128 tile
template <int RELU>
__global__ __launch_bounds__(256) void gemm_bt(const unsigned short* __restrict__ A,
                                               const unsigned short* __restrict__ Bt,
                                               const float* __restrict__ bias,
                                               unsigned short* __restrict__ C,
                                               int M, int N, int K) {
    __shared__ __align__(16) unsigned short As[128 * 32];
    __shared__ __align__(16) unsigned short Bs[128 * 32];
    const int tid = threadIdx.x;
    const int w = tid >> 6, l = tid & 63;
    const int wr = w >> 1, wc = w & 1;
    const int bm = blockIdx.x, bn = blockIdx.y;
    const int l15 = l & 15, l4 = l >> 4;

    f32x4 acc[4][4] = {};

    const long long a_base = (long long)bm * 128 * K;
    const long long b_base = (long long)bn * 128 * K;

    for (int k0 = 0; k0 < K; k0 += 32) {
#pragma unroll
        for (int i = 0; i < 2; ++i) {
            const int fl = i * 256 + tid;
            const int row = fl >> 2, kq = (fl & 3) << 3;
            __builtin_amdgcn_global_load_lds(
                (const __attribute__((address_space(1))) void*)(A + a_base + (long long)row * K + k0 + kq),
                (__attribute__((address_space(3))) void*)(&As[fl * 8]), 16, 0, 0);
            __builtin_amdgcn_global_load_lds(
                (const __attribute__((address_space(1))) void*)(Bt + b_base + (long long)row * K + k0 + kq),
                (__attribute__((address_space(3))) void*)(&Bs[fl * 8]), 16, 0, 0);
        }
        __syncthreads();

        short8 a[4], b[4];
#pragma unroll
        for (int m = 0; m < 4; ++m)
            a[m] = *(const short8*)(As + (wr * 64 + m * 16 + l15) * 32 + l4 * 8);
#pragma unroll
        for (int n = 0; n < 4; ++n)
            b[n] = *(const short8*)(Bs + (wc * 64 + n * 16 + l15) * 32 + l4 * 8);
#pragma unroll
        for (int m = 0; m < 4; ++m)
#pragma unroll
            for (int n = 0; n < 4; ++n)
                acc[m][n] = __builtin_amdgcn_mfma_f32_16x16x32_bf16(a[m], b[n], acc[m][n], 0, 0, 0);
        __syncthreads();
    }

#pragma unroll
    for (int m = 0; m < 4; ++m) {
        const int grow_base = bm * 128 + wr * 64 + m * 16 + l4 * 4;
#pragma unroll
        for (int n = 0; n < 4; ++n) {
            const int gcol = bn * 128 + wc * 64 + n * 16 + l15;
            const float bv = bias[gcol];
#pragma unroll
            for (int j = 0; j < 4; ++j) {
                float v = acc[m][n][j] + bv;
                if (RELU) v = fmaxf(v, 0.0f);
                C[(long long)(grow_base + j) * N + gcol] = f2bf(v);
            }
        }
    }
}

// ---------------- 6. final 512-dot + sigmoid -------------------------------
__global__ __launch_bounds__(256) void final_kernel(const unsigned short* __restrict__ h2,
                                                    const float* __restrict__ W3,
                                                    const float* __restrict__ b3,
                                                    float* __restrict__ out) {
    __shared__ float w3s[512];
    const int tid = threadIdx.x;
    w3s[tid] = W3[tid];
    w3s[tid + 256] = W3[tid + 256];
    __syncthreads();
    const int wv = tid >> 6, l = tid & 63;
    const long long row = (long long)blockIdx.x * 4 + wv;
    const u16x8 h = *(const u16x8*)(h2 + row * 512 + l * 8);
    float acc = 0.f;
#pragma unroll
    for (int j = 0; j < 8; ++j) acc += bf2f(h[j]) * w3s[l * 8 + j];
#pragma unroll
    for (int off = 32; off > 0; off >>= 1) acc += __shfl_xor(acc, off, 64);
    if (l == 0) out[row] = 1.0f / (1.0f + expf(-(acc + b3[0])));
}

// ---------------- host ------------------------------------------------------
extern "C" void kernel_launch(void* const* d_in, const int* in_sizes, int n_in,
                              void* d_out, int out_size, void* d_ws, size_t ws_size,
                              hipStream_t stream) {
    const int*   idx = (const int*)d_in[0];
    const float* emb = (const float*)d_in[1];
    const float* W1  = (const float*)d_in[2];
    const float* b1  = (const float*)d_in[3];
    const float* W2  = (const float*)d_in[4];
    const float* b2  = (const float*)d_in[5];
    const float* W3  = (const float*)d_in[6];
    const float* b3  = (const float*)d_in[7];
    float* out = (float*)d_out;

    char* ws = (char*)d_ws;
    unsigned short* xb  = (unsigned short*)ws; ws += (size_t)BATCH * DW * 2;
    unsigned short* h1  = (unsigned short*)ws; ws += (size_t)BATCH * DW * 2;
    unsigned short* h2  = (unsigned short*)ws; ws += (size_t)BATCH * 512 * 2;
    unsigned short* w1t = (unsigned short*)ws; ws += (size_t)1024 * 1024 * 2;
    unsigned short* w2t = (unsigned short*)ws; ws += (size_t)512 * 1024 * 2;
    float* ssum = (float*)ws; ws += 4096;
    float* ssq  = (float*)ws; ws += 4096;
    float* mean = (float*)ws; ws += 4096;
    float* rsig = (float*)ws; ws += 4096;

    hipMemsetAsync(ssum, 0, 8192, stream);   // ssum + ssq are contiguous

    pool_kernel<<<(BATCH * NF * 4) / 256, 256, 0, stream>>>(idx, emb, xb);
    stats_kernel<<<BATCH / 128, 256, 0, stream>>>(xb, ssum, ssq);
    finalize_stats<<<4, 256, 0, stream>>>(ssum, ssq, mean, rsig);
    normalize_kernel<<<(BATCH * DW / 8) / 256, 256, 0, stream>>>(xb, mean, rsig);

    transpose_f32_bf16<<<dim3(32, 32), 256, 0, stream>>>(W1, w1t, 1024, 1024);
    transpose_f32_bf16<<<dim3(16, 32), 256, 0, stream>>>(W2, w2t, 1024, 512);

    gemm_bt<1><<<dim3(BATCH / 128, 1024 / 128), 256, 0, stream>>>(xb, w1t, b1, h1, BATCH, 1024, 1024);
    gemm_bt<1><<<dim3(BATCH / 128, 512 / 128), 256, 0, stream>>>(h1, w2t, b2, h2, BATCH, 512, 1024);

    final_kernel<<<BATCH / 4, 256, 0, stream>>>(h2, W3, b3, out);
}

// Round 4
// 325.825 us; speedup vs baseline: 1.0069x; 1.0069x over previous
//
#include <hip/hip_runtime.h>
#include <hip/hip_bf16.h>
#include <math.h>

typedef __attribute__((ext_vector_type(8))) short  short8;
typedef __attribute__((ext_vector_type(4))) float  f32x4;
typedef __attribute__((ext_vector_type(4))) unsigned short u16x4;
typedef __attribute__((ext_vector_type(8))) unsigned short u16x8;

#define BATCH 16384
#define NF    64
#define BAGL  10
#define ED    16
#define DW    1024   // F*E
#define VOCAB 1000000

static __device__ __forceinline__ unsigned short f2bf(float f) {
    unsigned int u = __builtin_bit_cast(unsigned int, f);
    unsigned int r = (u + 0x7fffu + ((u >> 16) & 1u)) >> 16;
    return (unsigned short)r;
}
static __device__ __forceinline__ float bf2f(unsigned short h) {
    unsigned int u = ((unsigned int)h) << 16;
    return __builtin_bit_cast(float, u);
}

// ---------------- 0. emb f32 [V,16] -> bf16 table (halves gather set) ------
__global__ __launch_bounds__(256) void emb_to_bf16(const float* __restrict__ e,
                                                   unsigned short* __restrict__ o) {
    const long long i = ((long long)blockIdx.x * 256 + threadIdx.x) * 8;
    if (i >= (long long)VOCAB * ED) return;           // ceil-grid guard
    const f32x4 a = *(const f32x4*)(e + i);
    const f32x4 b = *(const f32x4*)(e + i + 4);
    u16x8 r;
#pragma unroll
    for (int j = 0; j < 4; ++j) { r[j] = f2bf(a[j]); r[4 + j] = f2bf(b[j]); }
    *(u16x8*)(o + i) = r;
}

// ---------------- 1. gather + bag-sum from bf16 table ----------------------
// 2 threads/bag, 16B (8 cols) each; all 10 gathers issued before accumulation.
__global__ __launch_bounds__(256) void pool_bf16(const int* __restrict__ idx,
                                                 const unsigned short* __restrict__ embb,
                                                 unsigned short* __restrict__ xb) {
    const int gid = blockIdx.x * 256 + threadIdx.x;   // B*F*2 threads
    const int bag = gid >> 1;
    const int h   = gid & 1;                          // row half
    const int* ip = idx + (long long)bag * BAGL;

    int v[BAGL];
#pragma unroll
    for (int l = 0; l < BAGL; ++l) v[l] = ip[l];
    u16x8 e[BAGL];
#pragma unroll
    for (int l = 0; l < BAGL; ++l)
        e[l] = *(const u16x8*)(embb + (((long long)v[l]) << 4) + h * 8);

    float s[8] = {0, 0, 0, 0, 0, 0, 0, 0};
#pragma unroll
    for (int l = 0; l < BAGL; ++l)
#pragma unroll
        for (int j = 0; j < 8; ++j) s[j] += bf2f(e[l][j]);

    u16x8 o;
#pragma unroll
    for (int j = 0; j < 8; ++j) o[j] = f2bf(s[j]);
    *(u16x8*)(xb + (((long long)bag) << 4) + h * 8) = o;
}

// ---------------- 2. per-column sum / sumsq over batch ---------------------
__global__ __launch_bounds__(256) void stats_kernel(const unsigned short* __restrict__ xb,
                                                    float* __restrict__ ssum,
                                                    float* __restrict__ ssq) {
    const int t = threadIdx.x;                 // cols 4t..4t+3
    const long long r0 = (long long)blockIdx.x * 128;
    float s[4] = {0, 0, 0, 0}, q[4] = {0, 0, 0, 0};
    for (int r = 0; r < 128; ++r) {
        const u16x4 v = *(const u16x4*)(xb + (r0 + r) * DW + t * 4);
#pragma unroll
        for (int j = 0; j < 4; ++j) { float f = bf2f(v[j]); s[j] += f; q[j] += f * f; }
    }
#pragma unroll
    for (int j = 0; j < 4; ++j) {
        atomicAdd(&ssum[t * 4 + j], s[j]);
        atomicAdd(&ssq [t * 4 + j], q[j]);
    }
}

__global__ void finalize_stats(const float* __restrict__ ssum, const float* __restrict__ ssq,
                               float* __restrict__ mean, float* __restrict__ rsig,
                               float* __restrict__ murs) {
    const int c = blockIdx.x * 256 + threadIdx.x;    // 1024 total
    const float m = ssum[c] * (1.0f / (float)BATCH);
    const float v = ssq[c] * (1.0f / (float)BATCH) - m * m;
    const float r = rsqrtf(v + 1e-5f);
    mean[c] = m; rsig[c] = r; murs[c] = m * r;
}

// ---------------- 3. W [R,C] f32 -> Wt [C,R] bf16, optional row-scale ------
template <int SCALE>
__global__ __launch_bounds__(256) void transpose_f32_bf16(const float* __restrict__ src,
                                                          unsigned short* __restrict__ dst,
                                                          int R, int C,
                                                          const float* __restrict__ rs) {
    __shared__ float tile[32][33];
    const int tx = threadIdx.x & 31, ty = threadIdx.x >> 5;
    const int bx = blockIdx.x, by = blockIdx.y;
#pragma unroll
    for (int i = 0; i < 4; ++i) {
        const int r = by * 32 + ty + i * 8, c = bx * 32 + tx;
        float v = src[(long long)r * C + c];
        if (SCALE) v *= rs[r];
        tile[ty + i * 8][tx] = v;
    }
    __syncthreads();
#pragma unroll
    for (int i = 0; i < 4; ++i) {
        const int oc = bx * 32 + ty + i * 8;     // column index -> row of dst
        dst[(long long)oc * R + by * 32 + tx] = f2bf(tile[tx][ty + i * 8]);
    }
}

// ---------------- 3b. b1n[n] -= sum_k murs[k]*W1[k,n]  (BN fold bias) ------
__global__ __launch_bounds__(256) void b1fold_kernel(const float* __restrict__ W1,
                                                     const float* __restrict__ murs,
                                                     float* __restrict__ b1n) {
    const int n = blockIdx.x * 256 + threadIdx.x;    // grid (4, 8)
    const int k0 = blockIdx.y * 128;
    float acc = 0.f;
#pragma unroll 4
    for (int k = 0; k < 128; ++k)
        acc += murs[k0 + k] * W1[(long long)(k0 + k) * 1024 + n];
    atomicAdd(&b1n[n], -acc);
}

// ---------------- 5. bf16 MFMA GEMM, 128x128 tile, BK=64, XCD swizzle ------
// A [M,K] bf16 rm, Bt [N,K] bf16 rm, C = relu(A@Bt^T + bias + bias2), bf16
__global__ __launch_bounds__(256) void gemm_relu(const unsigned short* __restrict__ A,
                                                 const unsigned short* __restrict__ Bt,
                                                 const float* __restrict__ bias,
                                                 const float* __restrict__ bias2,
                                                 unsigned short* __restrict__ C,
                                                 int M, int N, int K, int NBN) {
    __shared__ __align__(16) unsigned short As[128 * 64];
    __shared__ __align__(16) unsigned short Bs[128 * 64];
    const int tid = threadIdx.x;
    const int w = tid >> 6, l = tid & 63;
    const int wr = w >> 1, wc = w & 1;
    // XCD-chunked swizzle: each XCD owns 16 contiguous bm panels
    const int blk = blockIdx.x, xcd = blk & 7, j = blk >> 3;
    const int bm = xcd * 16 + j / NBN, bn = j % NBN;
    const int l15 = l & 15, l4 = l >> 4;

    f32x4 acc[4][4] = {};
    const long long a_base = (long long)bm * 128 * K;
    const long long b_base = (long long)bn * 128 * K;

    for (int k0 = 0; k0 < K; k0 += 64) {
#pragma unroll
        for (int i = 0; i < 4; ++i) {
            const int cid = i * 256 + tid;
            const int row = cid >> 3, kq = (cid & 7) << 3;
            __builtin_amdgcn_global_load_lds(
                (const __attribute__((address_space(1))) void*)(A + a_base + (long long)row * K + k0 + kq),
                (__attribute__((address_space(3))) void*)(&As[cid * 8]), 16, 0, 0);
            __builtin_amdgcn_global_load_lds(
                (const __attribute__((address_space(1))) void*)(Bt + b_base + (long long)row * K + k0 + kq),
                (__attribute__((address_space(3))) void*)(&Bs[cid * 8]), 16, 0, 0);
        }
        __syncthreads();

        short8 a[2][4], b[2][4];
#pragma unroll
        for (int kk = 0; kk < 2; ++kk) {
#pragma unroll
            for (int m = 0; m < 4; ++m)
                a[kk][m] = *(const short8*)(As + (wr * 64 + m * 16 + l15) * 64 + kk * 32 + l4 * 8);
#pragma unroll
            for (int n = 0; n < 4; ++n)
                b[kk][n] = *(const short8*)(Bs + (wc * 64 + n * 16 + l15) * 64 + kk * 32 + l4 * 8);
        }
#pragma unroll
        for (int kk = 0; kk < 2; ++kk)
#pragma unroll
            for (int m = 0; m < 4; ++m)
#pragma unroll
                for (int n = 0; n < 4; ++n)
                    acc[m][n] = __builtin_amdgcn_mfma_f32_16x16x32_bf16(a[kk][m], b[kk][n], acc[m][n], 0, 0, 0);
        __syncthreads();
    }

#pragma unroll
    for (int m = 0; m < 4; ++m) {
        const int grow_base = bm * 128 + wr * 64 + m * 16 + l4 * 4;
#pragma unroll
        for (int n = 0; n < 4; ++n) {
            const int gcol = bn * 128 + wc * 64 + n * 16 + l15;
            const float bv = bias[gcol] + (bias2 ? bias2[gcol] : 0.f);
#pragma unroll
            for (int j2 = 0; j2 < 4; ++j2) {
                float v = fmaxf(acc[m][n][j2] + bv, 0.f);
                C[(long long)(grow_base + j2) * N + gcol] = f2bf(v);
            }
        }
    }
}

// ---------------- 5b. GEMM2 with fused W3-dot epilogue ---------------------
// logits[row] += sum_col relu(h2[row,col]) * W3[col]
__global__ __launch_bounds__(256) void gemm2_fused(const unsigned short* __restrict__ A,
                                                   const unsigned short* __restrict__ Bt,
                                                   const float* __restrict__ bias,
                                                   const float* __restrict__ W3,
                                                   float* __restrict__ logits,
                                                   int M, int N, int K, int NBN) {
    __shared__ __align__(16) unsigned short As[128 * 64];
    __shared__ __align__(16) unsigned short Bs[128 * 64];
    const int tid = threadIdx.x;
    const int w = tid >> 6, l = tid & 63;
    const int wr = w >> 1, wc = w & 1;
    const int blk = blockIdx.x, xcd = blk & 7, j = blk >> 3;
    const int bm = xcd * 16 + j / NBN, bn = j % NBN;
    const int l15 = l & 15, l4 = l >> 4;

    f32x4 acc[4][4] = {};
    const long long a_base = (long long)bm * 128 * K;
    const long long b_base = (long long)bn * 128 * K;

    for (int k0 = 0; k0 < K; k0 += 64) {
#pragma unroll
        for (int i = 0; i < 4; ++i) {
            const int cid = i * 256 + tid;
            const int row = cid >> 3, kq = (cid & 7) << 3;
            __builtin_amdgcn_global_load_lds(
                (const __attribute__((address_space(1))) void*)(A + a_base + (long long)row * K + k0 + kq),
                (__attribute__((address_space(3))) void*)(&As[cid * 8]), 16, 0, 0);
            __builtin_amdgcn_global_load_lds(
                (const __attribute__((address_space(1))) void*)(Bt + b_base + (long long)row * K + k0 + kq),
                (__attribute__((address_space(3))) void*)(&Bs[cid * 8]), 16, 0, 0);
        }
        __syncthreads();

        short8 a[2][4], b[2][4];
#pragma unroll
        for (int kk = 0; kk < 2; ++kk) {
#pragma unroll
            for (int m = 0; m < 4; ++m)
                a[kk][m] = *(const short8*)(As + (wr * 64 + m * 16 + l15) * 64 + kk * 32 + l4 * 8);
#pragma unroll
            for (int n = 0; n < 4; ++n)
                b[kk][n] = *(const short8*)(Bs + (wc * 64 + n * 16 + l15) * 64 + kk * 32 + l4 * 8);
        }
#pragma unroll
        for (int kk = 0; kk < 2; ++kk)
#pragma unroll
            for (int m = 0; m < 4; ++m)
#pragma unroll
                for (int n = 0; n < 4; ++n)
                    acc[m][n] = __builtin_amdgcn_mfma_f32_16x16x32_bf16(a[kk][m], b[kk][n], acc[m][n], 0, 0, 0);
        __syncthreads();
    }

#pragma unroll
    for (int m = 0; m < 4; ++m) {
        float part[4] = {0.f, 0.f, 0.f, 0.f};
#pragma unroll
        for (int n = 0; n < 4; ++n) {
            const int gcol = bn * 128 + wc * 64 + n * 16 + l15;
            const float bv = bias[gcol];
            const float w3 = W3[gcol];
#pragma unroll
            for (int j2 = 0; j2 < 4; ++j2) {
                float v = fmaxf(acc[m][n][j2] + bv, 0.f);
                part[j2] += v * w3;
            }
        }
#pragma unroll
        for (int off = 1; off < 16; off <<= 1)
#pragma unroll
            for (int j2 = 0; j2 < 4; ++j2) part[j2] += __shfl_xor(part[j2], off, 64);
        if (l15 == 0) {
            const int grow = bm * 128 + wr * 64 + m * 16 + l4 * 4;
#pragma unroll
            for (int j2 = 0; j2 < 4; ++j2) atomicAdd(&logits[grow + j2], part[j2]);
        }
    }
}

// ---------------- 6. sigmoid ------------------------------------------------
__global__ __launch_bounds__(256) void sigmoid_kernel(const float* __restrict__ logits,
                                                      const float* __restrict__ b3,
                                                      float* __restrict__ out) {
    const int i = blockIdx.x * 256 + threadIdx.x;
    out[i] = 1.0f / (1.0f + expf(-(logits[i] + b3[0])));
}

// ---------------- host ------------------------------------------------------
extern "C" void kernel_launch(void* const* d_in, const int* in_sizes, int n_in,
                              void* d_out, int out_size, void* d_ws, size_t ws_size,
                              hipStream_t stream) {
    const int*   idx = (const int*)d_in[0];
    const float* emb = (const float*)d_in[1];
    const float* W1  = (const float*)d_in[2];
    const float* b1  = (const float*)d_in[3];
    const float* W2  = (const float*)d_in[4];
    const float* b2  = (const float*)d_in[5];
    const float* W3  = (const float*)d_in[6];
    const float* b3  = (const float*)d_in[7];
    float* out = (float*)d_out;

    // union region for embb (bf16 table, 32.0MB) then h1 (33.6MB) — h1 is the
    // larger; sizing the union by h1 fixes the round-3 overlap-clobber bug.
    const size_t EMBB_H1_BYTES = (size_t)BATCH * DW * 2;   // 33,554,432 >= VOCAB*ED*2

    char* ws = (char*)d_ws;
    unsigned short* xb   = (unsigned short*)ws; ws += (size_t)BATCH * DW * 2;   // 32MB
    unsigned short* embb = (unsigned short*)ws; ws += EMBB_H1_BYTES;            // 32MB+pad
    unsigned short* h1   = embb;  // gemm1 output overwrites dead bf16 table
    unsigned short* w1t  = (unsigned short*)ws; ws += (size_t)1024 * 1024 * 2;  // 2MB
    unsigned short* w2t  = (unsigned short*)ws; ws += (size_t)512 * 1024 * 2;   // 1MB
    // accumulated buffers (zeroed): ssum, ssq, b1n, logits — contiguous
    float* ssum   = (float*)ws; ws += 4096;
    float* ssq    = (float*)ws; ws += 4096;
    float* b1n    = (float*)ws; ws += 4096;
    float* logits = (float*)ws; ws += (size_t)BATCH * 4;
    float* mean   = (float*)ws; ws += 4096;
    float* rsig   = (float*)ws; ws += 4096;
    float* murs   = (float*)ws; ws += 4096;

    hipMemsetAsync(ssum, 0, 4096 * 3 + (size_t)BATCH * 4, stream);

    const long long embElems = (long long)VOCAB * ED;          // 16,000,000
    const int embBlocks = (int)((embElems / 8 + 255) / 256);   // ceil
    emb_to_bf16<<<embBlocks, 256, 0, stream>>>(emb, embb);
    pool_bf16<<<(BATCH * NF * 2) / 256, 256, 0, stream>>>(idx, embb, xb);
    stats_kernel<<<BATCH / 128, 256, 0, stream>>>(xb, ssum, ssq);
    finalize_stats<<<4, 256, 0, stream>>>(ssum, ssq, mean, rsig, murs);

    transpose_f32_bf16<1><<<dim3(32, 32), 256, 0, stream>>>(W1, w1t, 1024, 1024, rsig);
    b1fold_kernel<<<dim3(4, 8), 256, 0, stream>>>(W1, murs, b1n);
    transpose_f32_bf16<0><<<dim3(16, 32), 256, 0, stream>>>(W2, w2t, 1024, 512, nullptr);

    gemm_relu<<<(BATCH / 128) * (1024 / 128), 256, 0, stream>>>(
        xb, w1t, b1, b1n, h1, BATCH, 1024, 1024, 1024 / 128);
    gemm2_fused<<<(BATCH / 128) * (512 / 128), 256, 0, stream>>>(
        h1, w2t, b2, W3, logits, BATCH, 512, 1024, 512 / 128);

    sigmoid_kernel<<<BATCH / 256, 256, 0, stream>>>(logits, b3, out);
}

// Round 5
// 295.521 us; speedup vs baseline: 1.1102x; 1.1025x over previous
//
#include <hip/hip_runtime.h>
#include <hip/hip_bf16.h>
#include <math.h>

typedef __attribute__((ext_vector_type(8))) short  short8;
typedef __attribute__((ext_vector_type(4))) float  f32x4;
typedef __attribute__((ext_vector_type(4))) unsigned short u16x4;
typedef __attribute__((ext_vector_type(8))) unsigned short u16x8;

#define BATCH 16384
#define NF    64
#define BAGL  10
#define ED    16
#define DW    1024   // F*E
#define VOCAB 1000000

static __device__ __forceinline__ unsigned short f2bf(float f) {
    unsigned int u = __builtin_bit_cast(unsigned int, f);
    unsigned int r = (u + 0x7fffu + ((u >> 16) & 1u)) >> 16;
    return (unsigned short)r;
}
static __device__ __forceinline__ float bf2f(unsigned short h) {
    unsigned int u = ((unsigned int)h) << 16;
    return __builtin_bit_cast(float, u);
}

// ---------------- 0. emb f32 [V,16] -> bf16 table --------------------------
__global__ __launch_bounds__(256) void emb_to_bf16(const float* __restrict__ e,
                                                   unsigned short* __restrict__ o) {
    const long long i = ((long long)blockIdx.x * 256 + threadIdx.x) * 8;
    if (i >= (long long)VOCAB * ED) return;           // ceil-grid guard
    const f32x4 a = *(const f32x4*)(e + i);
    const f32x4 b = *(const f32x4*)(e + i + 4);
    u16x8 r;
#pragma unroll
    for (int j = 0; j < 4; ++j) { r[j] = f2bf(a[j]); r[4 + j] = f2bf(b[j]); }
    *(u16x8*)(o + i) = r;
}

// ---------------- 1. gather + bag-sum from bf16 table ----------------------
__global__ __launch_bounds__(256) void pool_bf16(const int* __restrict__ idx,
                                                 const unsigned short* __restrict__ embb,
                                                 unsigned short* __restrict__ xb) {
    const int gid = blockIdx.x * 256 + threadIdx.x;   // B*F*2 threads
    const int bag = gid >> 1;
    const int h   = gid & 1;                          // row half
    const int* ip = idx + (long long)bag * BAGL;

    int v[BAGL];
#pragma unroll
    for (int l = 0; l < BAGL; ++l) v[l] = ip[l];
    u16x8 e[BAGL];
#pragma unroll
    for (int l = 0; l < BAGL; ++l)
        e[l] = *(const u16x8*)(embb + (((long long)v[l]) << 4) + h * 8);

    float s[8] = {0, 0, 0, 0, 0, 0, 0, 0};
#pragma unroll
    for (int l = 0; l < BAGL; ++l)
#pragma unroll
        for (int j = 0; j < 8; ++j) s[j] += bf2f(e[l][j]);

    u16x8 o;
#pragma unroll
    for (int j = 0; j < 8; ++j) o[j] = f2bf(s[j]);
    *(u16x8*)(xb + (((long long)bag) << 4) + h * 8) = o;
}

// ---------------- 2. per-column sum / sumsq over batch ---------------------
__global__ __launch_bounds__(256) void stats_kernel(const unsigned short* __restrict__ xb,
                                                    float* __restrict__ ssum,
                                                    float* __restrict__ ssq) {
    const int t = threadIdx.x;                 // cols 4t..4t+3
    const long long r0 = (long long)blockIdx.x * 128;
    float s[4] = {0, 0, 0, 0}, q[4] = {0, 0, 0, 0};
    for (int r = 0; r < 128; ++r) {
        const u16x4 v = *(const u16x4*)(xb + (r0 + r) * DW + t * 4);
#pragma unroll
        for (int j = 0; j < 4; ++j) { float f = bf2f(v[j]); s[j] += f; q[j] += f * f; }
    }
#pragma unroll
    for (int j = 0; j < 4; ++j) {
        atomicAdd(&ssum[t * 4 + j], s[j]);
        atomicAdd(&ssq [t * 4 + j], q[j]);
    }
}

__global__ void finalize_stats(const float* __restrict__ ssum, const float* __restrict__ ssq,
                               float* __restrict__ mean, float* __restrict__ rsig,
                               float* __restrict__ murs) {
    const int c = blockIdx.x * 256 + threadIdx.x;    // 1024 total
    const float m = ssum[c] * (1.0f / (float)BATCH);
    const float v = ssq[c] * (1.0f / (float)BATCH) - m * m;
    const float r = rsqrtf(v + 1e-5f);
    mean[c] = m; rsig[c] = r; murs[c] = m * r;
}

// ---------------- 3. W [R,C] f32 -> Wt [C,R] bf16, optional row-scale ------
template <int SCALE>
__global__ __launch_bounds__(256) void transpose_f32_bf16(const float* __restrict__ src,
                                                          unsigned short* __restrict__ dst,
                                                          int R, int C,
                                                          const float* __restrict__ rs) {
    __shared__ float tile[32][33];
    const int tx = threadIdx.x & 31, ty = threadIdx.x >> 5;
    const int bx = blockIdx.x, by = blockIdx.y;
#pragma unroll
    for (int i = 0; i < 4; ++i) {
        const int r = by * 32 + ty + i * 8, c = bx * 32 + tx;
        float v = src[(long long)r * C + c];
        if (SCALE) v *= rs[r];
        tile[ty + i * 8][tx] = v;
    }
    __syncthreads();
#pragma unroll
    for (int i = 0; i < 4; ++i) {
        const int oc = bx * 32 + ty + i * 8;     // column index -> row of dst
        dst[(long long)oc * R + by * 32 + tx] = f2bf(tile[tx][ty + i * 8]);
    }
}

// ---------------- 3b. b1n[n] -= sum_k murs[k]*W1[k,n]  (BN fold bias) ------
__global__ __launch_bounds__(256) void b1fold_kernel(const float* __restrict__ W1,
                                                     const float* __restrict__ murs,
                                                     float* __restrict__ b1n) {
    const int n = blockIdx.x * 256 + threadIdx.x;    // grid (4, 8)
    const int k0 = blockIdx.y * 128;
    float acc = 0.f;
#pragma unroll 4
    for (int k = 0; k < 128; ++k)
        acc += murs[k0 + k] * W1[(long long)(k0 + k) * 1024 + n];
    atomicAdd(&b1n[n], -acc);
}

// ============ pipelined 128x128 bf16 GEMM core (T2+T3/T4+T5) ===============
// LDS chunk swizzle: 16B chunk at row r, pos p holds global chunk p^(r&7).
// Source address is inverse-permuted (rule 21); reads XOR the same way.
// Schedule per K-tile t (buf p=t&1, NT tiles, 8 gloads/tile):
//   ds_read(16 b128, buf p) ; lgkmcnt(0) ; barrier ;
//   stage(t+2 -> buf p) ; setprio1 ; 32 MFMA ; setprio0 ;
//   vmcnt(8) ; barrier          (never 0 mid-loop)
#define GEMM_STAGE(dstA, dstB, kt)                                              \
  {                                                                             \
    const int k0s = (kt) * 64;                                                  \
    _Pragma("unroll")                                                           \
    for (int g = 0; g < 4; ++g) {                                               \
      const int cid = g * 256 + tid;                                            \
      const int rr = cid >> 3, pos = cid & 7;                                   \
      const int csrc = (pos ^ (rr & 7)) << 3;                                   \
      __builtin_amdgcn_global_load_lds(                                         \
        (const __attribute__((address_space(1))) void*)(A + a_base + (long long)rr * K + k0s + csrc), \
        (__attribute__((address_space(3))) void*)(&(dstA)[cid * 8]), 16, 0, 0); \
      __builtin_amdgcn_global_load_lds(                                         \
        (const __attribute__((address_space(1))) void*)(Bt + b_base + (long long)rr * K + k0s + csrc), \
        (__attribute__((address_space(3))) void*)(&(dstB)[cid * 8]), 16, 0, 0); \
    }                                                                           \
  }

#define GEMM_CORE_LOOP                                                          \
    const int tid = threadIdx.x;                                                \
    const int w = tid >> 6, l = tid & 63;                                       \
    const int wr = w >> 1, wc = w & 1;                                          \
    const int l15 = l & 15, l4 = l >> 4;                                        \
    f32x4 acc[4][4] = {};                                                       \
    const long long a_base = (long long)bm * 128 * K;                           \
    const long long b_base = (long long)bn * 128 * K;                           \
    const int NT = K >> 6;                                                      \
    GEMM_STAGE(As[0], Bs[0], 0)                                                 \
    GEMM_STAGE(As[1], Bs[1], 1)                                                 \
    asm volatile("s_waitcnt vmcnt(8)" ::: "memory");                            \
    __builtin_amdgcn_sched_barrier(0);                                          \
    __builtin_amdgcn_s_barrier();                                               \
    for (int t = 0; t < NT; ++t) {                                              \
        const unsigned short* Ap = As[t & 1];                                   \
        const unsigned short* Bp = Bs[t & 1];                                   \
        short8 a[2][4], b[2][4];                                                \
        _Pragma("unroll")                                                       \
        for (int kk = 0; kk < 2; ++kk) {                                        \
            const int swz = ((kk * 4 + l4) ^ (l15 & 7)) << 3;                   \
            _Pragma("unroll")                                                   \
            for (int m = 0; m < 4; ++m)                                         \
                a[kk][m] = *(const short8*)(Ap + (wr * 64 + m * 16 + l15) * 64 + swz); \
            _Pragma("unroll")                                                   \
            for (int n = 0; n < 4; ++n)                                         \
                b[kk][n] = *(const short8*)(Bp + (wc * 64 + n * 16 + l15) * 64 + swz); \
        }                                                                       \
        asm volatile("s_waitcnt lgkmcnt(0)" ::: "memory");                      \
        __builtin_amdgcn_sched_barrier(0);                                      \
        __builtin_amdgcn_s_barrier();                                           \
        if (t + 2 < NT) { GEMM_STAGE(As[t & 1], Bs[t & 1], t + 2) }             \
        __builtin_amdgcn_s_setprio(1);                                          \
        _Pragma("unroll")                                                       \
        for (int kk = 0; kk < 2; ++kk)                                          \
            _Pragma("unroll")                                                   \
            for (int m = 0; m < 4; ++m)                                         \
                _Pragma("unroll")                                               \
                for (int n = 0; n < 4; ++n)                                     \
                    acc[m][n] = __builtin_amdgcn_mfma_f32_16x16x32_bf16(        \
                        a[kk][m], b[kk][n], acc[m][n], 0, 0, 0);                \
        __builtin_amdgcn_s_setprio(0);                                          \
        if (t + 1 < NT) {                                                       \
            if (t + 2 < NT) { asm volatile("s_waitcnt vmcnt(8)" ::: "memory"); }\
            else            { asm volatile("s_waitcnt vmcnt(0)" ::: "memory"); }\
            __builtin_amdgcn_sched_barrier(0);                                  \
            __builtin_amdgcn_s_barrier();                                       \
        }                                                                       \
    }

// ---------------- 5. GEMM1: C = relu(A@Bt^T + bias + bias2), bf16 ----------
__global__ __launch_bounds__(256, 2) void gemm_relu(const unsigned short* __restrict__ A,
                                                    const unsigned short* __restrict__ Bt,
                                                    const float* __restrict__ bias,
                                                    const float* __restrict__ bias2,
                                                    unsigned short* __restrict__ C,
                                                    int M, int N, int K, int NBN) {
    __shared__ __align__(16) unsigned short As[2][128 * 64];
    __shared__ __align__(16) unsigned short Bs[2][128 * 64];
    const int blk = blockIdx.x, xcd = blk & 7, j = blk >> 3;
    const int bm = xcd * 16 + j / NBN, bn = j % NBN;

    GEMM_CORE_LOOP

#pragma unroll
    for (int m = 0; m < 4; ++m) {
        const int grow_base = bm * 128 + wr * 64 + m * 16 + l4 * 4;
#pragma unroll
        for (int n = 0; n < 4; ++n) {
            const int gcol = bn * 128 + wc * 64 + n * 16 + l15;
            const float bv = bias[gcol] + bias2[gcol];
#pragma unroll
            for (int j2 = 0; j2 < 4; ++j2) {
                float v = fmaxf(acc[m][n][j2] + bv, 0.f);
                C[(long long)(grow_base + j2) * N + gcol] = f2bf(v);
            }
        }
    }
}

// ---------------- 5b. GEMM2 with fused W3-dot epilogue ---------------------
__global__ __launch_bounds__(256, 2) void gemm2_fused(const unsigned short* __restrict__ A,
                                                      const unsigned short* __restrict__ Bt,
                                                      const float* __restrict__ bias,
                                                      const float* __restrict__ W3,
                                                      float* __restrict__ logits,
                                                      int M, int N, int K, int NBN) {
    __shared__ __align__(16) unsigned short As[2][128 * 64];
    __shared__ __align__(16) unsigned short Bs[2][128 * 64];
    const int blk = blockIdx.x, xcd = blk & 7, j = blk >> 3;
    const int bm = xcd * 16 + j / NBN, bn = j % NBN;

    GEMM_CORE_LOOP

#pragma unroll
    for (int m = 0; m < 4; ++m) {
        float part[4] = {0.f, 0.f, 0.f, 0.f};
#pragma unroll
        for (int n = 0; n < 4; ++n) {
            const int gcol = bn * 128 + wc * 64 + n * 16 + l15;
            const float bv = bias[gcol];
            const float w3 = W3[gcol];
#pragma unroll
            for (int j2 = 0; j2 < 4; ++j2) {
                float v = fmaxf(acc[m][n][j2] + bv, 0.f);
                part[j2] += v * w3;
            }
        }
#pragma unroll
        for (int off = 1; off < 16; off <<= 1)
#pragma unroll
            for (int j2 = 0; j2 < 4; ++j2) part[j2] += __shfl_xor(part[j2], off, 64);
        if (l15 == 0) {
            const int grow = bm * 128 + wr * 64 + m * 16 + l4 * 4;
#pragma unroll
            for (int j2 = 0; j2 < 4; ++j2) atomicAdd(&logits[grow + j2], part[j2]);
        }
    }
}

// ---------------- 6. sigmoid ------------------------------------------------
__global__ __launch_bounds__(256) void sigmoid_kernel(const float* __restrict__ logits,
                                                      const float* __restrict__ b3,
                                                      float* __restrict__ out) {
    const int i = blockIdx.x * 256 + threadIdx.x;
    out[i] = 1.0f / (1.0f + expf(-(logits[i] + b3[0])));
}

// ---------------- host ------------------------------------------------------
extern "C" void kernel_launch(void* const* d_in, const int* in_sizes, int n_in,
                              void* d_out, int out_size, void* d_ws, size_t ws_size,
                              hipStream_t stream) {
    const int*   idx = (const int*)d_in[0];
    const float* emb = (const float*)d_in[1];
    const float* W1  = (const float*)d_in[2];
    const float* b1  = (const float*)d_in[3];
    const float* W2  = (const float*)d_in[4];
    const float* b2  = (const float*)d_in[5];
    const float* W3  = (const float*)d_in[6];
    const float* b3  = (const float*)d_in[7];
    float* out = (float*)d_out;

    // union region: embb (bf16 table, 32.0MB) then h1 (33.6MB) — sized by h1.
    const size_t EMBB_H1_BYTES = (size_t)BATCH * DW * 2;   // 33,554,432

    char* ws = (char*)d_ws;
    unsigned short* xb   = (unsigned short*)ws; ws += (size_t)BATCH * DW * 2;   // 32MB
    unsigned short* embb = (unsigned short*)ws; ws += EMBB_H1_BYTES;            // 32MB+
    unsigned short* h1   = embb;  // gemm1 output overwrites dead bf16 table
    unsigned short* w1t  = (unsigned short*)ws; ws += (size_t)1024 * 1024 * 2;  // 2MB
    unsigned short* w2t  = (unsigned short*)ws; ws += (size_t)512 * 1024 * 2;   // 1MB
    float* ssum   = (float*)ws; ws += 4096;
    float* ssq    = (float*)ws; ws += 4096;
    float* b1n    = (float*)ws; ws += 4096;
    float* logits = (float*)ws; ws += (size_t)BATCH * 4;
    float* mean   = (float*)ws; ws += 4096;
    float* rsig   = (float*)ws; ws += 4096;
    float* murs   = (float*)ws; ws += 4096;

    hipMemsetAsync(ssum, 0, 4096 * 3 + (size_t)BATCH * 4, stream);

    const long long embElems = (long long)VOCAB * ED;          // 16,000,000
    const int embBlocks = (int)((embElems / 8 + 255) / 256);   // ceil
    emb_to_bf16<<<embBlocks, 256, 0, stream>>>(emb, embb);
    pool_bf16<<<(BATCH * NF * 2) / 256, 256, 0, stream>>>(idx, embb, xb);
    stats_kernel<<<BATCH / 128, 256, 0, stream>>>(xb, ssum, ssq);
    finalize_stats<<<4, 256, 0, stream>>>(ssum, ssq, mean, rsig, murs);

    transpose_f32_bf16<1><<<dim3(32, 32), 256, 0, stream>>>(W1, w1t, 1024, 1024, rsig);
    b1fold_kernel<<<dim3(4, 8), 256, 0, stream>>>(W1, murs, b1n);
    transpose_f32_bf16<0><<<dim3(16, 32), 256, 0, stream>>>(W2, w2t, 1024, 512, nullptr);

    gemm_relu<<<(BATCH / 128) * (1024 / 128), 256, 0, stream>>>(
        xb, w1t, b1, b1n, h1, BATCH, 1024, 1024, 1024 / 128);
    gemm2_fused<<<(BATCH / 128) * (512 / 128), 256, 0, stream>>>(
        h1, w2t, b2, W3, logits, BATCH, 512, 1024, 512 / 128);

    sigmoid_kernel<<<BATCH / 256, 256, 0, stream>>>(logits, b3, out);
}